// Round 2
// baseline (201.307 us; speedup 1.0000x reference)
//
#include <hip/hip_runtime.h>
#include <hip/hip_bf16.h>

// Problem constants (match reference)
#define BB 32
#define SS 512
#define HH 1024
#define MM 8
#define NROWS (BB*SS)        // 16384 token rows
#define NSPANS (BB*SS*MM)    // 131072 spans
#define KSEL 4915            // int(0.3 * B * S)

// Workspace layout (bytes)
constexpr size_t OFF_QUERY = 0;                   // 1024 f32
constexpr size_t OFF_QD    = 4096;                // 16384 f32
constexpr size_t OFF_SD    = OFF_QD + 65536;      // 16384 f32
constexpr size_t OFF_KEYS  = OFF_SD + 65536;      // 131072 u32
constexpr size_t OFF_GOLD  = OFF_KEYS + 524288;   // 131072 u32
constexpr size_t OFF_HIST  = OFF_GOLD + 524288;   // 65536 u32
constexpr size_t OFF_HIST2 = OFF_HIST + 262144;   // 65536 u32
constexpr size_t OFF_EQ    = OFF_HIST2 + 262144;  // 4096 u32
constexpr size_t OFF_SCAL  = OFF_EQ + 16384;      // scalars
constexpr size_t ZERO_FROM  = OFF_HIST;
constexpr size_t ZERO_BYTES = (OFF_SCAL + 64) - OFF_HIST;

struct Scal {
    float loss_sum;      // 0
    unsigned n_valid;    // 1
    unsigned Bt;         // 2  high-16 bucket holding K-th key
    unsigned R;          // 3  rank needed within that bucket
    unsigned tau;        // 4  exact 32-bit threshold key
    unsigned T;          // 5  how many entries == tau are taken
    unsigned right_gt;   // 6  gold count among key > tau
    unsigned eq_count;   // 7  entries == tau
};

__device__ __forceinline__ unsigned sortable_key(float f) {
    unsigned b = __float_as_uint(f);
    return (b & 0x80000000u) ? ~b : (b | 0x80000000u);
}

// ---- K1: query = w_in @ term_weight + b_in (one wave per output row) ----
__global__ void k_query(const float* __restrict__ w_in, const float* __restrict__ tw,
                        const float* __restrict__ b_in, float* __restrict__ query) {
    int wave = (blockIdx.x * blockDim.x + threadIdx.x) >> 6;
    int lane = threadIdx.x & 63;
    if (wave >= HH) return;
    const float4* wrow = (const float4*)(w_in + (size_t)wave * HH);
    const float4* tv   = (const float4*)tw;
    float s = 0.f;
    #pragma unroll
    for (int p = 0; p < 4; ++p) {
        int c = p * 64 + lane;
        float4 w = wrow[c]; float4 t = tv[c];
        s += w.x*t.x + w.y*t.y + w.z*t.z + w.w*t.w;
    }
    #pragma unroll
    for (int o = 32; o > 0; o >>= 1) s += __shfl_down(s, o);
    if (lane == 0) query[wave] = s + b_in[wave];
}

// ---- K2: qd/sd = hidden · {query, score_w}, one wave per token row ----
__global__ void k_dots(const float* __restrict__ hs, const float* __restrict__ query,
                       const float* __restrict__ sw, float* __restrict__ qd,
                       float* __restrict__ sd) {
    int wave = (blockIdx.x * blockDim.x + threadIdx.x) >> 6;
    int lane = threadIdx.x & 63;
    if (wave >= NROWS) return;
    const float4* row = (const float4*)(hs + (size_t)wave * HH);
    const float4* qv  = (const float4*)query;
    const float4* sv  = (const float4*)sw;
    float a = 0.f, c2 = 0.f;
    #pragma unroll
    for (int p = 0; p < 4; ++p) {
        int c = p * 64 + lane;
        float4 h = row[c]; float4 q = qv[c]; float4 w = sv[c];
        a  += h.x*q.x + h.y*q.y + h.z*q.z + h.w*q.w;
        c2 += h.x*w.x + h.y*w.y + h.z*w.z + h.w*w.w;
    }
    #pragma unroll
    for (int o = 32; o > 0; o >>= 1) { a += __shfl_down(a, o); c2 += __shfl_down(c2, o); }
    if (lane == 0) { qd[wave] = a; sd[wave] = c2; }
}

// ---- K3: per-(b,s) online softmax -> scores, keys, gold flags, hist, loss ----
__global__ void k_scores(const float* __restrict__ qd, const float* __restrict__ sd,
                         const int* __restrict__ gold_mask, const int* __restrict__ seq_lengths,
                         const float* __restrict__ score_b_p,
                         unsigned* __restrict__ keys, unsigned* __restrict__ goldf,
                         unsigned* __restrict__ hist, Scal* sc) {
    int t = blockIdx.x * blockDim.x + threadIdx.x;   // [0, NROWS)
    float lloss = 0.f; int lval = 0;
    {
        int b = t >> 9, s = t & (SS - 1);
        int seqlen = seq_lengths[b];
        float sb = *score_b_p;
        float maxv = 0.f, den = 0.f, num = 0.f;
        #pragma unroll
        for (int m = 0; m < MM; ++m) {
            int pos = s + m; if (pos > SS - 1) pos = SS - 1;
            float x = qd[b * SS + pos];
            float v = sd[b * SS + pos];
            if (m == 0)         { maxv = x; den = 1.f; num = v; }
            else if (x > maxv)  { float e = expf(maxv - x); den = den * e + 1.f; num = num * e + v; maxv = x; }
            else                { float e = expf(x - maxv); den += e; num += e * v; }
            float score = num / den + sb;
            int idx = t * MM + m;
            bool valid = (s + m + 1) <= seqlen;
            bool gold  = valid && (gold_mask[idx] == 0);
            unsigned key = valid ? sortable_key(score) : 0u;
            keys[idx]  = key;
            goldf[idx] = gold ? 1u : 0u;
            if (valid) {
                atomicAdd(&hist[key >> 16], 1u);
                lval++;
                float z = -score;
                float sp = (z > 0.f) ? (z + log1pf(expf(-z))) : log1pf(expf(z));
                lloss += gold ? sp : 0.69314718055994531f;
            }
        }
    }
    __shared__ float lsum[256];
    __shared__ int   lcnt[256];
    lsum[threadIdx.x] = lloss; lcnt[threadIdx.x] = lval;
    __syncthreads();
    for (int o = 128; o > 0; o >>= 1) {
        if (threadIdx.x < o) { lsum[threadIdx.x] += lsum[threadIdx.x + o]; lcnt[threadIdx.x] += lcnt[threadIdx.x + o]; }
        __syncthreads();
    }
    if (threadIdx.x == 0) {
        atomicAdd(&sc->loss_sum, lsum[0]);
        atomicAdd(&sc->n_valid, (unsigned)lcnt[0]);
    }
}

// ---- K4: find high-16 bucket containing K-th largest ----
__global__ void k_sel1(const unsigned* __restrict__ hist, Scal* sc) {
    __shared__ unsigned csum[256];
    unsigned s = 0; int base = threadIdx.x * 256;
    for (int i = 0; i < 256; ++i) s += hist[base + i];
    csum[threadIdx.x] = s;
    __syncthreads();
    if (threadIdx.x == 0) {
        unsigned cum = 0; int c = 255;
        for (; c > 0; --c) { if (cum + csum[c] >= KSEL) break; cum += csum[c]; }
        int bt = c * 256;
        for (int bk = c * 256 + 255; bk >= c * 256; --bk) {
            unsigned h = hist[bk];
            if (cum + h >= KSEL) { bt = bk; break; }
            cum += h;
        }
        sc->Bt = (unsigned)bt;
        sc->R  = KSEL - cum;
    }
}

// ---- K5: low-16 histogram of keys inside the boundary bucket ----
__global__ void k_hist2(const unsigned* __restrict__ keys, unsigned* __restrict__ hist2,
                        const Scal* sc) {
    unsigned bt = sc->Bt;
    for (int i = blockIdx.x * blockDim.x + threadIdx.x; i < NSPANS; i += gridDim.x * blockDim.x) {
        unsigned k = keys[i];
        if ((k >> 16) == bt) atomicAdd(&hist2[k & 0xFFFFu], 1u);
    }
}

// ---- K6: exact threshold key tau and count T taken at tau ----
__global__ void k_sel2(const unsigned* __restrict__ hist2, Scal* sc) {
    __shared__ unsigned csum[256];
    unsigned R = sc->R;
    unsigned s = 0; int base = threadIdx.x * 256;
    for (int i = 0; i < 256; ++i) s += hist2[base + i];
    csum[threadIdx.x] = s;
    __syncthreads();
    if (threadIdx.x == 0) {
        unsigned cum = 0; int c = 255;
        for (; c > 0; --c) { if (cum + csum[c] >= R) break; cum += csum[c]; }
        int j = c * 256;
        for (int bk = c * 256 + 255; bk >= c * 256; --bk) {
            unsigned h = hist2[bk];
            if (cum + h >= R) { j = bk; break; }
            cum += h;
        }
        sc->tau = (sc->Bt << 16) | (unsigned)j;
        sc->T   = R - cum;
    }
}

// ---- K7: gold count above tau; collect indices equal to tau ----
__global__ void k_count(const unsigned* __restrict__ keys, const unsigned* __restrict__ goldf,
                        unsigned* __restrict__ eqList, Scal* sc) {
    unsigned tau = sc->tau;
    int lgt = 0;
    for (int i = blockIdx.x * blockDim.x + threadIdx.x; i < NSPANS; i += gridDim.x * blockDim.x) {
        unsigned k = keys[i];
        if (k > tau) lgt += (int)goldf[i];
        else if (k == tau) {
            unsigned p = atomicAdd(&sc->eq_count, 1u);
            if (p < 4096) eqList[p] = (unsigned)i;
        }
    }
    #pragma unroll
    for (int o = 32; o > 0; o >>= 1) lgt += __shfl_down(lgt, o);
    if ((threadIdx.x & 63) == 0 && lgt) atomicAdd(&sc->right_gt, (unsigned)lgt);
}

// ---- K8: resolve ties (lowest-index-first, matching lax.top_k), finalize ----
// NOTE: d_out is float32 (reference returns float32 scalars). Round-1 failure
// decoded exactly to bf16-halves-packed-into-float misread.
__global__ void k_final(const unsigned* __restrict__ goldf, const unsigned* __restrict__ eqList,
                        const Scal* sc, float* __restrict__ out) {
    if (blockIdx.x != 0 || threadIdx.x != 0) return;
    unsigned T = sc->T;
    unsigned neq = sc->eq_count; if (neq > 4096) neq = 4096;
    unsigned extra = 0;
    if (T >= neq) {
        for (unsigned i = 0; i < neq; ++i) extra += goldf[eqList[i]];
    } else {
        unsigned prev = 0; bool first = true;
        for (unsigned it = 0; it < T; ++it) {
            unsigned mn = 0xFFFFFFFFu;
            for (unsigned i = 0; i < neq; ++i) {
                unsigned v = eqList[i];
                if ((first || v > prev) && v < mn) mn = v;
            }
            if (mn == 0xFFFFFFFFu) break;
            extra += goldf[mn];
            prev = mn; first = false;
        }
    }
    float loss = sc->loss_sum / (float)sc->n_valid;
    float prec = (float)(sc->right_gt + extra) / (float)KSEL;
    out[0] = loss;
    out[1] = prec;
}

extern "C" void kernel_launch(void* const* d_in, const int* in_sizes, int n_in,
                              void* d_out, int out_size, void* d_ws, size_t ws_size,
                              hipStream_t stream) {
    const float* hidden   = (const float*)d_in[0];
    const float* term_w   = (const float*)d_in[1];
    const float* w_in     = (const float*)d_in[2];
    const float* b_in     = (const float*)d_in[3];
    const float* score_w  = (const float*)d_in[4];
    const float* score_b  = (const float*)d_in[5];
    const int*   seq_len  = (const int*)d_in[6];
    const int*   gmask    = (const int*)d_in[7];
    float* out            = (float*)d_out;

    char* ws = (char*)d_ws;
    float*    query = (float*)(ws + OFF_QUERY);
    float*    qd    = (float*)(ws + OFF_QD);
    float*    sd    = (float*)(ws + OFF_SD);
    unsigned* keys  = (unsigned*)(ws + OFF_KEYS);
    unsigned* goldf = (unsigned*)(ws + OFF_GOLD);
    unsigned* hist  = (unsigned*)(ws + OFF_HIST);
    unsigned* hist2 = (unsigned*)(ws + OFF_HIST2);
    unsigned* eqL   = (unsigned*)(ws + OFF_EQ);
    Scal*     sc    = (Scal*)(ws + OFF_SCAL);

    hipMemsetAsync(ws + ZERO_FROM, 0, ZERO_BYTES, stream);

    k_query <<<256, 256, 0, stream>>>(w_in, term_w, b_in, query);
    k_dots  <<<4096, 256, 0, stream>>>(hidden, query, score_w, qd, sd);
    k_scores<<<64, 256, 0, stream>>>(qd, sd, gmask, seq_len, score_b, keys, goldf, hist, sc);
    k_sel1  <<<1, 256, 0, stream>>>(hist, sc);
    k_hist2 <<<128, 256, 0, stream>>>(keys, hist2, sc);
    k_sel2  <<<1, 256, 0, stream>>>(hist2, sc);
    k_count <<<128, 256, 0, stream>>>(keys, goldf, eqL, sc);
    k_final <<<1, 64, 0, stream>>>(goldf, eqL, sc, out);
}

// Round 3
// 151.197 us; speedup vs baseline: 1.3314x; 1.3314x over previous
//
#include <hip/hip_runtime.h>

// Problem constants (match reference)
#define BB 32
#define SS 512
#define HH 1024
#define MM 8
#define NROWS (BB*SS)        // 16384 token rows
#define NSPANS (BB*SS*MM)    // 131072 spans
#define KSEL 4915            // int(0.3 * B * S)

// Workspace layout (bytes)
constexpr size_t OFF_QUERY = 0;                   // 1024 f32
constexpr size_t OFF_QD    = 4096;                // 16384 f32
constexpr size_t OFF_SD    = OFF_QD + 65536;      // 16384 f32
constexpr size_t OFF_KEYS  = OFF_SD + 65536;      // 131072 u32
constexpr size_t OFF_GOLD  = OFF_KEYS + 524288;   // 131072 u32
constexpr size_t OFF_H0    = OFF_GOLD + 524288;   // 256 u32
constexpr size_t OFF_H1    = OFF_H0 + 1024;       // 256 u32
constexpr size_t OFF_H2    = OFF_H1 + 1024;       // 256 u32
constexpr size_t OFF_H3    = OFF_H2 + 1024;       // 256 u32
constexpr size_t OFF_SCAL  = OFF_H3 + 1024;       // scalars (64 B)
constexpr size_t OFF_EQ    = OFF_SCAL + 64;       // 4096 u32 (not zeroed)
constexpr size_t ZERO_FROM  = OFF_H0;
constexpr size_t ZERO_BYTES = OFF_EQ - OFF_H0;    // hists + scalars

struct Scal {
    float    loss_sum;
    unsigned n_valid;
    unsigned p8,  R0;    // after level-0 sel (written by h-level-1 kernel)
    unsigned p16, R1;    // 16-bit prefix      (written by h-level-2 kernel)
    unsigned p24, R2;    // 24-bit prefix      (written by h-level-3 kernel)
    unsigned tau, T;     // exact threshold    (written by k_count)
    unsigned right_gt, eq_count;
};

__device__ __forceinline__ unsigned sortable_key(float f) {
    unsigned b = __float_as_uint(f);
    return (b & 0x80000000u) ? ~b : (b | 0x80000000u);
}

// ---- K1: query = w_in @ term_weight + b_in (one wave per output row) ----
__global__ void k_query(const float* __restrict__ w_in, const float* __restrict__ tw,
                        const float* __restrict__ b_in, float* __restrict__ query) {
    int wave = (blockIdx.x * blockDim.x + threadIdx.x) >> 6;
    int lane = threadIdx.x & 63;
    if (wave >= HH) return;
    const float4* wrow = (const float4*)(w_in + (size_t)wave * HH);
    const float4* tv   = (const float4*)tw;
    float s = 0.f;
    #pragma unroll
    for (int p = 0; p < 4; ++p) {
        int c = p * 64 + lane;
        float4 w = wrow[c]; float4 t = tv[c];
        s += w.x*t.x + w.y*t.y + w.z*t.z + w.w*t.w;
    }
    #pragma unroll
    for (int o = 32; o > 0; o >>= 1) s += __shfl_down(s, o);
    if (lane == 0) query[wave] = s + b_in[wave];
}

// ---- K2: qd/sd = hidden · {query, score_w}, one wave per token row ----
__global__ void k_dots(const float* __restrict__ hs, const float* __restrict__ query,
                       const float* __restrict__ sw, float* __restrict__ qd,
                       float* __restrict__ sd) {
    int wave = (blockIdx.x * blockDim.x + threadIdx.x) >> 6;
    int lane = threadIdx.x & 63;
    if (wave >= NROWS) return;
    const float4* row = (const float4*)(hs + (size_t)wave * HH);
    const float4* qv  = (const float4*)query;
    const float4* sv  = (const float4*)sw;
    float a = 0.f, c2 = 0.f;
    #pragma unroll
    for (int p = 0; p < 4; ++p) {
        int c = p * 64 + lane;
        float4 h = row[c]; float4 q = qv[c]; float4 w = sv[c];
        a  += h.x*q.x + h.y*q.y + h.z*q.z + h.w*q.w;
        c2 += h.x*w.x + h.y*w.y + h.z*w.z + h.w*w.w;
    }
    #pragma unroll
    for (int o = 32; o > 0; o >>= 1) { a += __shfl_down(a, o); c2 += __shfl_down(c2, o); }
    if (lane == 0) { qd[wave] = a; sd[wave] = c2; }
}

// ---- K3: per-(b,s) online softmax -> scores/keys/gold/loss + LDS hist0 ----
// Global-atomic histogram replaced by LDS-privatized 256-bin (top-8) hist:
// round-2 rocprof showed 53.8 us with VALUBusy 1.8% = same-address global
// atomic serialization on hot buckets.
__global__ void k_scores(const float* __restrict__ qd, const float* __restrict__ sd,
                         const int* __restrict__ gold_mask, const int* __restrict__ seq_lengths,
                         const float* __restrict__ score_b_p,
                         unsigned* __restrict__ keys, unsigned* __restrict__ goldf,
                         unsigned* __restrict__ hist0, Scal* sc) {
    __shared__ unsigned h0[256];
    __shared__ float lsum[256];
    __shared__ int   lcnt[256];
    h0[threadIdx.x] = 0;
    __syncthreads();

    int t = blockIdx.x * blockDim.x + threadIdx.x;   // [0, NROWS)
    int b = t >> 9, s = t & (SS - 1);
    int seqlen = seq_lengths[b];
    float sb = *score_b_p;

    uint4 gm0 = ((const uint4*)gold_mask)[t * 2];
    uint4 gm1 = ((const uint4*)gold_mask)[t * 2 + 1];
    unsigned gmv[8] = {gm0.x, gm0.y, gm0.z, gm0.w, gm1.x, gm1.y, gm1.z, gm1.w};

    unsigned kbuf[8], gbuf[8];
    float lloss = 0.f; int lval = 0;
    float maxv = 0.f, den = 0.f, num = 0.f;
    #pragma unroll
    for (int m = 0; m < MM; ++m) {
        int pos = s + m; if (pos > SS - 1) pos = SS - 1;
        float x = qd[b * SS + pos];
        float v = sd[b * SS + pos];
        if (m == 0)         { maxv = x; den = 1.f; num = v; }
        else if (x > maxv)  { float e = expf(maxv - x); den = den * e + 1.f; num = num * e + v; maxv = x; }
        else                { float e = expf(x - maxv); den += e; num += e * v; }
        float score = num / den + sb;
        bool valid = (s + m + 1) <= seqlen;
        bool gold  = valid && (gmv[m] == 0u);
        unsigned key = valid ? sortable_key(score) : 0u;
        kbuf[m] = key;
        gbuf[m] = gold ? 1u : 0u;
        if (valid) {
            atomicAdd(&h0[key >> 24], 1u);
            lval++;
            float z = -score;
            float sp = (z > 0.f) ? (z + log1pf(expf(-z))) : log1pf(expf(z));
            lloss += gold ? sp : 0.69314718055994531f;
        }
    }
    ((uint4*)keys)[t * 2]     = make_uint4(kbuf[0], kbuf[1], kbuf[2], kbuf[3]);
    ((uint4*)keys)[t * 2 + 1] = make_uint4(kbuf[4], kbuf[5], kbuf[6], kbuf[7]);
    ((uint4*)goldf)[t * 2]     = make_uint4(gbuf[0], gbuf[1], gbuf[2], gbuf[3]);
    ((uint4*)goldf)[t * 2 + 1] = make_uint4(gbuf[4], gbuf[5], gbuf[6], gbuf[7]);

    lsum[threadIdx.x] = lloss; lcnt[threadIdx.x] = lval;
    __syncthreads();
    // merge LDS hist -> global (256 distinct addresses, 64 blocks => light)
    unsigned hv = h0[threadIdx.x];
    if (hv) atomicAdd(&hist0[threadIdx.x], hv);
    for (int o = 128; o > 0; o >>= 1) {
        if (threadIdx.x < o) { lsum[threadIdx.x] += lsum[threadIdx.x + o]; lcnt[threadIdx.x] += lcnt[threadIdx.x + o]; }
        __syncthreads();
    }
    if (threadIdx.x == 0) {
        atomicAdd(&sc->loss_sum, lsum[0]);
        atomicAdd(&sc->n_valid, (unsigned)lcnt[0]);
    }
}

// ---- K4/5/6: radix level N — fused [sel over prev hist] + [next 8-bit hist] ----
// Every block redundantly computes the selection from the previous level's
// 256-bin hist (1 KB read), so no separate tiny sel dispatches are needed.
__global__ void k_hist8(const unsigned* __restrict__ keys,
                        const unsigned* __restrict__ prev_hist,
                        unsigned* __restrict__ out_hist,
                        Scal* sc, int level) {
    __shared__ unsigned sh[256];
    __shared__ unsigned sres[2];
    sh[threadIdx.x] = prev_hist[threadIdx.x];
    __syncthreads();
    if (threadIdx.x == 0) {
        unsigned Rin, pprev;
        if (level == 1)      { Rin = KSEL;    pprev = 0; }
        else if (level == 2) { Rin = sc->R0;  pprev = sc->p8; }
        else                 { Rin = sc->R1;  pprev = sc->p16; }
        unsigned cum = 0; int c = 255;
        for (; c > 0; --c) { unsigned h = sh[c]; if (cum + h >= Rin) break; cum += h; }
        sres[0] = (pprev << 8) | (unsigned)c;
        sres[1] = Rin - cum;
    }
    __syncthreads();
    unsigned pref = sres[0], newR = sres[1];
    if (blockIdx.x == 0 && threadIdx.x == 0) {
        if (level == 1)      { sc->p8  = pref; sc->R0 = newR; }
        else if (level == 2) { sc->p16 = pref; sc->R1 = newR; }
        else                 { sc->p24 = pref; sc->R2 = newR; }
    }
    sh[threadIdx.x] = 0;
    __syncthreads();
    int shift  = (level == 1) ? 16 : (level == 2) ? 8 : 0;
    int mshift = shift + 8;
    for (int i = blockIdx.x * blockDim.x + threadIdx.x; i < NSPANS; i += gridDim.x * blockDim.x) {
        unsigned k = keys[i];
        if (k != 0u && (k >> mshift) == pref) atomicAdd(&sh[(k >> shift) & 0xFFu], 1u);
    }
    __syncthreads();
    unsigned v = sh[threadIdx.x];
    if (v) atomicAdd(&out_hist[threadIdx.x], v);
}

// ---- K7: final sel (tau,T) + gold count above tau + collect ties ----
__global__ void k_count(const unsigned* __restrict__ keys, const unsigned* __restrict__ goldf,
                        const unsigned* __restrict__ hist3,
                        unsigned* __restrict__ eqList, Scal* sc) {
    __shared__ unsigned sh[256];
    __shared__ unsigned sres[2];
    sh[threadIdx.x] = hist3[threadIdx.x];
    __syncthreads();
    if (threadIdx.x == 0) {
        unsigned Rin = sc->R2, pprev = sc->p24;
        unsigned cum = 0; int c = 255;
        for (; c > 0; --c) { unsigned h = sh[c]; if (cum + h >= Rin) break; cum += h; }
        sres[0] = (pprev << 8) | (unsigned)c;
        sres[1] = Rin - cum;
    }
    __syncthreads();
    unsigned tau = sres[0], T = sres[1];
    if (blockIdx.x == 0 && threadIdx.x == 0) { sc->tau = tau; sc->T = T; }
    int lgt = 0;
    for (int i = blockIdx.x * blockDim.x + threadIdx.x; i < NSPANS; i += gridDim.x * blockDim.x) {
        unsigned k = keys[i];
        if (k > tau) lgt += (int)goldf[i];
        else if (k == tau) {
            unsigned p = atomicAdd(&sc->eq_count, 1u);
            if (p < 4096) eqList[p] = (unsigned)i;
        }
    }
    #pragma unroll
    for (int o = 32; o > 0; o >>= 1) lgt += __shfl_down(lgt, o);
    if ((threadIdx.x & 63) == 0 && lgt) atomicAdd(&sc->right_gt, (unsigned)lgt);
}

// ---- K8: resolve ties (lowest-index-first, matching lax.top_k), finalize ----
// d_out is float32 (reference returns float32 scalars).
__global__ void k_final(const unsigned* __restrict__ goldf, const unsigned* __restrict__ eqList,
                        const Scal* sc, float* __restrict__ out) {
    if (blockIdx.x != 0 || threadIdx.x != 0) return;
    unsigned T = sc->T;
    unsigned neq = sc->eq_count; if (neq > 4096) neq = 4096;
    unsigned extra = 0;
    if (T >= neq) {
        for (unsigned i = 0; i < neq; ++i) extra += goldf[eqList[i]];
    } else {
        unsigned prev = 0; bool first = true;
        for (unsigned it = 0; it < T; ++it) {
            unsigned mn = 0xFFFFFFFFu;
            for (unsigned i = 0; i < neq; ++i) {
                unsigned v = eqList[i];
                if ((first || v > prev) && v < mn) mn = v;
            }
            if (mn == 0xFFFFFFFFu) break;
            extra += goldf[mn];
            prev = mn; first = false;
        }
    }
    float loss = sc->loss_sum / (float)sc->n_valid;
    float prec = (float)(sc->right_gt + extra) / (float)KSEL;
    out[0] = loss;
    out[1] = prec;
}

extern "C" void kernel_launch(void* const* d_in, const int* in_sizes, int n_in,
                              void* d_out, int out_size, void* d_ws, size_t ws_size,
                              hipStream_t stream) {
    const float* hidden   = (const float*)d_in[0];
    const float* term_w   = (const float*)d_in[1];
    const float* w_in     = (const float*)d_in[2];
    const float* b_in     = (const float*)d_in[3];
    const float* score_w  = (const float*)d_in[4];
    const float* score_b  = (const float*)d_in[5];
    const int*   seq_len  = (const int*)d_in[6];
    const int*   gmask    = (const int*)d_in[7];
    float* out            = (float*)d_out;

    char* ws = (char*)d_ws;
    float*    query = (float*)(ws + OFF_QUERY);
    float*    qd    = (float*)(ws + OFF_QD);
    float*    sd    = (float*)(ws + OFF_SD);
    unsigned* keys  = (unsigned*)(ws + OFF_KEYS);
    unsigned* goldf = (unsigned*)(ws + OFF_GOLD);
    unsigned* h0    = (unsigned*)(ws + OFF_H0);
    unsigned* h1    = (unsigned*)(ws + OFF_H1);
    unsigned* h2    = (unsigned*)(ws + OFF_H2);
    unsigned* h3    = (unsigned*)(ws + OFF_H3);
    unsigned* eqL   = (unsigned*)(ws + OFF_EQ);
    Scal*     sc    = (Scal*)(ws + OFF_SCAL);

    hipMemsetAsync(ws + ZERO_FROM, 0, ZERO_BYTES, stream);

    k_query <<<256, 256, 0, stream>>>(w_in, term_w, b_in, query);
    k_dots  <<<4096, 256, 0, stream>>>(hidden, query, score_w, qd, sd);
    k_scores<<<64, 256, 0, stream>>>(qd, sd, gmask, seq_len, score_b, keys, goldf, h0, sc);
    k_hist8 <<<128, 256, 0, stream>>>(keys, h0, h1, sc, 1);
    k_hist8 <<<128, 256, 0, stream>>>(keys, h1, h2, sc, 2);
    k_hist8 <<<128, 256, 0, stream>>>(keys, h2, h3, sc, 3);
    k_count <<<128, 256, 0, stream>>>(keys, goldf, h3, eqL, sc);
    k_final <<<1, 64, 0, stream>>>(goldf, eqL, sc, out);
}